// Round 7
// baseline (583.923 us; speedup 1.0000x reference)
//
#include <hip/hip_runtime.h>
#include <hip/hip_cooperative_groups.h>
#include <cstdint>
#include <cstddef>
#include <math.h>

namespace cg = cooperative_groups;

typedef unsigned long long u64;

#define BB 4
#define NN 32768
#define DD 512
#define KK 8192
#define TILE 8192
#define LT 1024      // threads per block
#define VE 8         // sort elements per thread (TILE / LT)
#define NBLK 256     // one block per CU; cooperative co-residency guaranteed
#define SROWS 32     // score rows per wave (4 ILP groups of 8)
#define GROWS 8      // gather rows per wave (2 ILP groups of 4)

// ---------------- register-resident bitonic primitives (verified R6) ----------------
// Element i = VE*t + e. CE rule: lower = ((i&j)==0), up = ((i&stage)==0);
// take-min iff (lower == up). J compile-time (rule #20).

template<int J>
__device__ __forceinline__ void reg_ce(u64 v[VE], int base, int stage) {
#pragma unroll
    for (int e = 0; e < VE; ++e) {
        if ((e & J) == 0) {
            const int f = e | J;
            bool up = (((base + e) & stage) == 0);
            u64 a = v[e], b = v[f];
            bool sw = up ? (a > b) : (a < b);
            if (sw) { v[e] = b; v[f] = a; }
        }
    }
}

__device__ __forceinline__ void reg_tail(u64 v[VE], int base, int stage, int jmax) {
    if (jmax >= 4) reg_ce<4>(v, base, stage);
    if (jmax >= 2) reg_ce<2>(v, base, stage);
    reg_ce<1>(v, base, stage);
}

__device__ __forceinline__ void shfl_pass(u64 v[VE], int t, int base, int stage, int j) {
    int m = j >> 3;                       // lane xor mask (VE==8); no v[] runtime index
    bool lower = ((t & m) == 0);
#pragma unroll
    for (int e = 0; e < VE; ++e) {
        u64 pv = __shfl_xor(v[e], m, 64);
        bool up = (((base + e) & stage) == 0);
        bool tm = (lower == up);
        bool lt = v[e] < pv;
        v[e] = (tm == lt) ? v[e] : pv;
    }
}

__device__ __forceinline__ void lds_pass(u64 v[VE], unsigned* lo, unsigned* hi,
                                         int t, int base, int stage, int j) {
    __syncthreads();                      // protect WAR vs previous pass's reads
#pragma unroll
    for (int e = 0; e < VE; ++e) {
        lo[e * LT + t] = (unsigned)v[e];
        hi[e * LT + t] = (unsigned)(v[e] >> 32);
    }
    __syncthreads();
    int pt = t ^ (j >> 3);
    bool lower = ((t & (j >> 3)) == 0);
#pragma unroll
    for (int e = 0; e < VE; ++e) {
        u64 pv = ((u64)hi[e * LT + pt] << 32) | (u64)lo[e * LT + pt];
        bool up = (((base + e) & stage) == 0);
        bool tm = (lower == up);
        bool lt = v[e] < pv;
        v[e] = (tm == lt) ? v[e] : pv;
    }
}

// ---------------- single fused cooperative kernel ----------------
__global__ __launch_bounds__(LT, 4) void fused_kernel(const float* __restrict__ h,
                                                      const float* __restrict__ sf,
                                                      u64* __restrict__ keys,
                                                      float* __restrict__ out) {
    __shared__ unsigned lds_lo[TILE];
    __shared__ unsigned lds_hi[TILE];
    cg::grid_group grid = cg::this_grid();

    const int tid  = threadIdx.x;
    const int wave = blockIdx.x * (LT / 64) + (tid >> 6);   // 0..4095
    const int lane = tid & 63;

    // ================= Phase S: score (all blocks) =================
    {
        int b  = wave >> 10;                 // 1024 waves per batch
        int n0 = (wave & 1023) * SROWS;
        const float4* s4 = (const float4*)(sf) + (size_t)b * 128;
        float4 w0 = s4[lane], w1 = s4[lane + 64];
        for (int g = 0; g < SROWS / 8; ++g) {
            int nb = n0 + g * 8;
            const float4* hb = (const float4*)(h) + ((size_t)b * NN + nb) * 128;
            float4 r0[8], r1[8];
#pragma unroll
            for (int r = 0; r < 8; ++r) {    // 16 loads in flight
                r0[r] = hb[r * 128 + lane];
                r1[r] = hb[r * 128 + 64 + lane];
            }
            u64 mykey = 0;
#pragma unroll
            for (int r = 0; r < 8; ++r) {
                double acc = (double)r0[r].x * w0.x + (double)r0[r].y * w0.y +
                             (double)r0[r].z * w0.z + (double)r0[r].w * w0.w +
                             (double)r1[r].x * w1.x + (double)r1[r].y * w1.y +
                             (double)r1[r].z * w1.z + (double)r1[r].w * w1.w;
#pragma unroll
                for (int off = 32; off >= 1; off >>= 1)
                    acc += __shfl_xor(acc, off, 64);
                // f32 sigmoid pipeline — replicates reference tie-buckets
                // near saturation (validated round 2; do not change).
                float x = (float)acc;
                float e = expf(-x);
                float s = 1.0f / (1.0f + e);
                u64 key = ((u64)(~__float_as_uint(s)) << 32) | (unsigned)(nb + r);
                if (lane == r) mykey = key;
            }
            if (lane < 8)
                keys[((size_t)b << 15) + nb + lane] = mykey;
        }
    }
    __threadfence();
    grid.sync();

    // ================= Phase L: local sort of 8192-tiles (blocks 0..15) =================
    if (blockIdx.x < 16) {
        int b    = blockIdx.x >> 2;
        int tile = blockIdx.x & 3;
        u64* kb = keys + ((size_t)b << 15) + tile * TILE;
        int base = tid * VE;
        u64 v[VE];
#pragma unroll
        for (int q = 0; q < VE / 2; ++q) {
            ulonglong2 p = ((const ulonglong2*)(kb + base))[q];
            v[2 * q] = p.x; v[2 * q + 1] = p.y;
        }
        for (int stage = 2; stage <= TILE; stage <<= 1) {
            int j = stage >> 1;
            for (; j >= 512; j >>= 1) lds_pass(v, lds_lo, lds_hi, tid, base, stage, j);
            for (; j >= 8; j >>= 1)   shfl_pass(v, tid, base, stage, j);
            reg_tail(v, base, stage, (stage >> 1) < 4 ? (stage >> 1) : 4);
        }
#pragma unroll
        for (int q = 0; q < VE / 2; ++q) {
            ulonglong2 p; p.x = v[2 * q]; p.y = v[2 * q + 1];
            ((ulonglong2*)(kb + base))[q] = p;
        }
    }
    __threadfence();
    grid.sync();

    // ================= Phase M1: top-8192 merge, 4 runs -> 2 (blocks 0..7) =================
    if (blockIdx.x < 8) {
        int b = blockIdx.x >> 1;
        int p = blockIdx.x & 1;
        u64* A = keys + ((size_t)b << 15) + (size_t)p * 2 * TILE;
        u64* B = A + TILE;
        int base = tid * VE;
        u64 a[VE], rb[VE], v[VE];
#pragma unroll
        for (int q = 0; q < VE / 2; ++q) {
            ulonglong2 pa = ((const ulonglong2*)(A + base))[q];
            a[2 * q] = pa.x; a[2 * q + 1] = pa.y;
            ulonglong2 pb = ((const ulonglong2*)(B + (TILE - VE - base)))[q];
            rb[2 * q] = pb.x; rb[2 * q + 1] = pb.y;
        }
#pragma unroll
        for (int e = 0; e < VE; ++e) {
            u64 x = a[e], y = rb[VE - 1 - e];   // y = B[TILE-1-(base+e)]
            v[e] = x < y ? x : y;
        }
        const int stage = 2 * TILE;              // ascending everywhere
        int j = TILE >> 1;
        for (; j >= 512; j >>= 1) lds_pass(v, lds_lo, lds_hi, tid, base, stage, j);
        for (; j >= 8; j >>= 1)   shfl_pass(v, tid, base, stage, j);
        reg_tail(v, base, stage, 4);
#pragma unroll
        for (int q = 0; q < VE / 2; ++q) {
            ulonglong2 pv; pv.x = v[2 * q]; pv.y = v[2 * q + 1];
            ((ulonglong2*)(A + base))[q] = pv;
        }
    }
    __threadfence();
    grid.sync();

    // ================= Phase M2: top-8192 merge, 2 runs -> 1 (blocks 0..3) =================
    if (blockIdx.x < 4) {
        int b = blockIdx.x;
        u64* A = keys + ((size_t)b << 15);
        u64* B = A + 2 * TILE;
        int base = tid * VE;
        u64 a[VE], rb[VE], v[VE];
#pragma unroll
        for (int q = 0; q < VE / 2; ++q) {
            ulonglong2 pa = ((const ulonglong2*)(A + base))[q];
            a[2 * q] = pa.x; a[2 * q + 1] = pa.y;
            ulonglong2 pb = ((const ulonglong2*)(B + (TILE - VE - base)))[q];
            rb[2 * q] = pb.x; rb[2 * q + 1] = pb.y;
        }
#pragma unroll
        for (int e = 0; e < VE; ++e) {
            u64 x = a[e], y = rb[VE - 1 - e];
            v[e] = x < y ? x : y;
        }
        const int stage = 2 * TILE;
        int j = TILE >> 1;
        for (; j >= 512; j >>= 1) lds_pass(v, lds_lo, lds_hi, tid, base, stage, j);
        for (; j >= 8; j >>= 1)   shfl_pass(v, tid, base, stage, j);
        reg_tail(v, base, stage, 4);
#pragma unroll
        for (int q = 0; q < VE / 2; ++q) {
            ulonglong2 pv; pv.x = v[2 * q]; pv.y = v[2 * q + 1];
            ((ulonglong2*)(A + base))[q] = pv;
        }
    }
    __threadfence();
    grid.sync();

    // ================= Phase G: gather + scale (all blocks) =================
    {
        int b  = wave >> 10;                 // 1024 waves per batch
        int j0 = (wave & 1023) * GROWS;
        for (int g = 0; g < GROWS / 4; ++g) {
            int jb = j0 + g * 4;
            u64 k[4];
#pragma unroll
            for (int r = 0; r < 4; ++r)
                k[r] = keys[((size_t)b << 15) + jb + r];
            float4 x0[4], x1[4];
            const float4* srcp[4];
#pragma unroll
            for (int r = 0; r < 4; ++r) {    // 8 loads in flight
                int idx = (int)(unsigned)(k[r] & 0xFFFFFFFFu);
                srcp[r] = (const float4*)(h) + ((size_t)b * NN + idx) * 128;
                x0[r] = srcp[r][lane];
                x1[r] = srcp[r][lane + 64];
            }
#pragma unroll
            for (int r = 0; r < 4; ++r) {
                float vv = __uint_as_float(~(unsigned)(k[r] >> 32));
                float4* dst = (float4*)(out) + ((size_t)b * KK + jb + r) * 128;
                float4 a = x0[r], c = x1[r];
                a.x *= vv; a.y *= vv; a.z *= vv; a.w *= vv;
                c.x *= vv; c.y *= vv; c.z *= vv; c.w *= vv;
                dst[lane] = a;
                dst[lane + 64] = c;
            }
        }
    }
}

extern "C" void kernel_launch(void* const* d_in, const int* in_sizes, int n_in,
                              void* d_out, int out_size, void* d_ws, size_t ws_size,
                              hipStream_t stream) {
    const float* h  = (const float*)d_in[0];
    const float* sf = (const float*)d_in[1];
    float* out = (float*)d_out;
    u64* keys = (u64*)d_ws;    // 4*32768*8 = 1 MiB of the workspace

    void* args[] = { (void*)&h, (void*)&sf, (void*)&keys, (void*)&out };
    hipLaunchCooperativeKernel((const void*)fused_kernel, dim3(NBLK), dim3(LT),
                               args, 0, stream);
}

// Round 8
// 128.020 us; speedup vs baseline: 4.5612x; 4.5612x over previous
//
#include <hip/hip_runtime.h>
#include <cstdint>
#include <cstddef>
#include <math.h>

typedef unsigned long long u64;

#define BB 4
#define NN 32768
#define DD 512
#define KK 8192
#define RPW 8        // score: rows per wave
#define RPG 4        // gather: rows per wave

// ---------------- score kernel: RPW rows per wave (verified R6) ----------------
__global__ __launch_bounds__(256) void score_kernel(const float* __restrict__ h,
                                                    const float* __restrict__ sf,
                                                    u64* __restrict__ keys) {
    int wave = (blockIdx.x * 256 + threadIdx.x) >> 6;  // 0..16383
    int lane = threadIdx.x & 63;
    int b  = wave >> 12;                 // 4096 waves per batch
    int n0 = (wave & 4095) * RPW;
    const float4* s4 = (const float4*)(sf) + (size_t)b * 128;
    float4 w0 = s4[lane], w1 = s4[lane + 64];
    const float4* hb = (const float4*)(h) + ((size_t)b * NN + n0) * 128;
    float4 r0[RPW], r1[RPW];
#pragma unroll
    for (int r = 0; r < RPW; ++r) {      // issue all 16 loads before any use
        r0[r] = hb[r * 128 + lane];
        r1[r] = hb[r * 128 + 64 + lane];
    }
    u64 mykey = 0;
#pragma unroll
    for (int r = 0; r < RPW; ++r) {
        double acc = (double)r0[r].x * w0.x + (double)r0[r].y * w0.y +
                     (double)r0[r].z * w0.z + (double)r0[r].w * w0.w +
                     (double)r1[r].x * w1.x + (double)r1[r].y * w1.y +
                     (double)r1[r].z * w1.z + (double)r1[r].w * w1.w;
#pragma unroll
        for (int off = 32; off >= 1; off >>= 1)
            acc += __shfl_xor(acc, off, 64);
        // f32 sigmoid pipeline — replicates reference tie-buckets near
        // saturation (validated round 2; do not change).
        float x = (float)acc;
        float e = expf(-x);
        float s = 1.0f / (1.0f + e);
        u64 key = ((u64)(~__float_as_uint(s)) << 32) | (unsigned)(n0 + r);
        if (lane == r) mykey = key;
    }
    if (lane < RPW)
        keys[((size_t)b << 15) + n0 + lane] = mykey;
}

// ---------------- bitonic primitives (verified R6; lds stride templated) ----------------
// Element i = 8*t + e (within span). CE rule: lower=((i&j)==0), up=((base_i&stage)==0);
// take-min iff (lower == up). J compile-time (rule #20). `base` carries the
// BATCH-GLOBAL element index so directions compose across tiles (R2 convention).

template<int J>
__device__ __forceinline__ void reg_ce(u64 v[8], int base, int stage) {
#pragma unroll
    for (int e = 0; e < 8; ++e) {
        if ((e & J) == 0) {
            const int f = e | J;
            bool up = (((base + e) & stage) == 0);
            u64 a = v[e], b = v[f];
            bool sw = up ? (a > b) : (a < b);
            if (sw) { v[e] = b; v[f] = a; }
        }
    }
}

__device__ __forceinline__ void reg_tail(u64 v[8], int base, int stage, int jmax) {
    if (jmax >= 4) reg_ce<4>(v, base, stage);
    if (jmax >= 2) reg_ce<2>(v, base, stage);
    reg_ce<1>(v, base, stage);
}

__device__ __forceinline__ void shfl_pass(u64 v[8], int t, int base, int stage, int j) {
    int m = j >> 3;                       // lane xor mask; j<=256 -> m<=32 (in-wave)
    bool lower = ((t & m) == 0);
#pragma unroll
    for (int e = 0; e < 8; ++e) {
        u64 pv = __shfl_xor(v[e], m, 64);
        bool up = (((base + e) & stage) == 0);
        bool tm = (lower == up);
        bool lt = v[e] < pv;
        v[e] = (tm == lt) ? v[e] : pv;
    }
}

template<int LTP>
__device__ __forceinline__ void lds_pass(u64 v[8], unsigned* lo, unsigned* hi,
                                         int t, int base, int stage, int j) {
    __syncthreads();                      // WAR protection vs previous pass
#pragma unroll
    for (int e = 0; e < 8; ++e) {
        lo[e * LTP + t] = (unsigned)v[e];
        hi[e * LTP + t] = (unsigned)(v[e] >> 32);
    }
    __syncthreads();
    int pt = t ^ (j >> 3);
    bool lower = ((t & (j >> 3)) == 0);
#pragma unroll
    for (int e = 0; e < 8; ++e) {
        u64 pv = ((u64)hi[e * LTP + pt] << 32) | (u64)lo[e * LTP + pt];
        bool up = (((base + e) & stage) == 0);
        bool tm = (lower == up);
        bool lt = v[e] < pv;
        v[e] = (tm == lt) ? v[e] : pv;
    }
}

// ------------- sortdir: 2048-tile bitonic sort, direction by global index -------------
// 64 blocks x 256 thr. Produces 16 alternating asc/desc runs per batch.
__global__ __launch_bounds__(256) void sortdir_kernel(u64* __restrict__ keys) {
    __shared__ unsigned lo[2048];
    __shared__ unsigned hi[2048];
    int b = blockIdx.x >> 4, tl = blockIdx.x & 15;
    u64* kb = keys + ((size_t)b << 15) + tl * 2048;
    int t = threadIdx.x;
    int gb = tl * 2048 + t * 8;          // batch-global base for directions
    u64 v[8];
#pragma unroll
    for (int q = 0; q < 4; ++q) {
        ulonglong2 p = ((const ulonglong2*)(kb + t * 8))[q];
        v[2 * q] = p.x; v[2 * q + 1] = p.y;
    }
    for (int stage = 2; stage <= 2048; stage <<= 1) {
        int j = stage >> 1;
        for (; j >= 512; j >>= 1) lds_pass<256>(v, lo, hi, t, gb, stage, j);
        for (; j >= 8; j >>= 1)   shfl_pass(v, t, gb, stage, j);
        reg_tail(v, gb, stage, (stage >> 1) < 4 ? (stage >> 1) : 4);
    }
#pragma unroll
    for (int q = 0; q < 4; ++q) {
        ulonglong2 p; p.x = v[2 * q]; p.y = v[2 * q + 1];
        ((ulonglong2*)(kb + t * 8))[q] = p;
    }
}

// ------------- one grid-wide compare-exchange pass (verified R2) -------------
__global__ __launch_bounds__(256) void global_ce_kernel(u64* __restrict__ keys,
                                                        int stage, int j) {
    int pid = blockIdx.x * 256 + threadIdx.x;   // 0..65535 (4 batches x 16384 pairs)
    int b = pid >> 14;
    int p = pid & 16383;
    u64* kb = keys + ((size_t)b << 15);
    int i = ((p & ~(j - 1)) << 1) | (p & (j - 1));
    int l = i | j;
    bool asc = ((i & stage) == 0);
    u64 a = kb[i], c = kb[l];
    if ((a > c) == asc) { kb[i] = c; kb[l] = a; }
}

// ------------- finish a global stage inside 2048-spans: j=1024..1 -------------
__global__ __launch_bounds__(256) void finish_kernel(u64* __restrict__ keys, int stage) {
    __shared__ unsigned lo[2048];
    __shared__ unsigned hi[2048];
    int b = blockIdx.x >> 4, tl = blockIdx.x & 15;
    u64* kb = keys + ((size_t)b << 15) + tl * 2048;
    int t = threadIdx.x;
    int gb = tl * 2048 + t * 8;
    u64 v[8];
#pragma unroll
    for (int q = 0; q < 4; ++q) {
        ulonglong2 p = ((const ulonglong2*)(kb + t * 8))[q];
        v[2 * q] = p.x; v[2 * q + 1] = p.y;
    }
    int j = 1024;
    for (; j >= 512; j >>= 1) lds_pass<256>(v, lo, hi, t, gb, stage, j);
    for (; j >= 8; j >>= 1)   shfl_pass(v, t, gb, stage, j);
    reg_tail(v, gb, stage, 4);
#pragma unroll
    for (int q = 0; q < 4; ++q) {
        ulonglong2 p; p.x = v[2 * q]; p.y = v[2 * q + 1];
        ((ulonglong2*)(kb + t * 8))[q] = p;
    }
}

// ------------- top-8192 of (asc A, desc B) adjacent runs: min-pair + asc sweep -------------
// [A|B] is bitonic (asc then desc); min(A[i],B[i]) = lower half of bitonic split,
// contains the 8192 smallest; 13-pass asc sweep sorts it. Result -> A's slot.
__global__ __launch_bounds__(1024) void topkAB_kernel(u64* __restrict__ keys) {
    __shared__ unsigned lo[8192];
    __shared__ unsigned hi[8192];
    int b = blockIdx.x >> 1, pr = blockIdx.x & 1;
    u64* A = keys + ((size_t)b << 15) + (size_t)pr * 16384;
    u64* B = A + 8192;
    int t = threadIdx.x, base = t * 8;
    u64 v[8];
#pragma unroll
    for (int q = 0; q < 4; ++q) {
        ulonglong2 pa = ((const ulonglong2*)(A + base))[q];
        ulonglong2 pb = ((const ulonglong2*)(B + base))[q];
        v[2 * q]     = pa.x < pb.x ? pa.x : pb.x;
        v[2 * q + 1] = pa.y < pb.y ? pa.y : pb.y;
    }
    const int stage = 32768;              // (base+e)&stage==0 -> ascending everywhere
    int j = 4096;
    for (; j >= 512; j >>= 1) lds_pass<1024>(v, lo, hi, t, base, stage, j);
    for (; j >= 8; j >>= 1)   shfl_pass(v, t, base, stage, j);
    reg_tail(v, base, stage, 4);
#pragma unroll
    for (int q = 0; q < 4; ++q) {
        ulonglong2 pv; pv.x = v[2 * q]; pv.y = v[2 * q + 1];
        ((ulonglong2*)(A + base))[q] = pv;
    }
}

// ------------- top-8192 of two ASC runs (A at 0, B at +16384), reversed-B (verified R6) -------------
__global__ __launch_bounds__(1024) void topk_rev_kernel(u64* __restrict__ keys) {
    __shared__ unsigned lo[8192];
    __shared__ unsigned hi[8192];
    int b = blockIdx.x;
    u64* A = keys + ((size_t)b << 15);
    u64* B = A + 16384;
    int t = threadIdx.x, base = t * 8;
    u64 a[8], rb[8], v[8];
#pragma unroll
    for (int q = 0; q < 4; ++q) {
        ulonglong2 pa = ((const ulonglong2*)(A + base))[q];
        a[2 * q] = pa.x; a[2 * q + 1] = pa.y;
        ulonglong2 pb = ((const ulonglong2*)(B + (8192 - 8 - base)))[q];
        rb[2 * q] = pb.x; rb[2 * q + 1] = pb.y;
    }
#pragma unroll
    for (int e = 0; e < 8; ++e) {
        u64 x = a[e], y = rb[7 - e];      // y = B[8191-(base+e)]
        v[e] = x < y ? x : y;
    }
    const int stage = 32768;
    int j = 4096;
    for (; j >= 512; j >>= 1) lds_pass<1024>(v, lo, hi, t, base, stage, j);
    for (; j >= 8; j >>= 1)   shfl_pass(v, t, base, stage, j);
    reg_tail(v, base, stage, 4);
#pragma unroll
    for (int q = 0; q < 4; ++q) {
        ulonglong2 pv; pv.x = v[2 * q]; pv.y = v[2 * q + 1];
        ((ulonglong2*)(A + base))[q] = pv;
    }
}

// ---------------- gather + scale: RPG rows per wave (verified R6) ----------------
__global__ __launch_bounds__(256) void gather_kernel(const float* __restrict__ h,
                                                     const u64* __restrict__ keys,
                                                     float* __restrict__ out) {
    int wave = (blockIdx.x * 256 + threadIdx.x) >> 6;  // 0..8191
    int lane = threadIdx.x & 63;
    int b  = wave >> 11;
    int j0 = (wave & 2047) * RPG;
    u64 k[RPG];
#pragma unroll
    for (int r = 0; r < RPG; ++r)
        k[r] = keys[((size_t)b << 15) + j0 + r];
    float4 x0[RPG], x1[RPG];
    const float4* srcp[RPG];
#pragma unroll
    for (int r = 0; r < RPG; ++r) {      // 8 loads in flight
        int idx = (int)(unsigned)(k[r] & 0xFFFFFFFFu);
        srcp[r] = (const float4*)(h) + ((size_t)b * NN + idx) * 128;
        x0[r] = srcp[r][lane];
        x1[r] = srcp[r][lane + 64];
    }
#pragma unroll
    for (int r = 0; r < RPG; ++r) {
        float v = __uint_as_float(~(unsigned)(k[r] >> 32));
        float4* dst = (float4*)(out) + ((size_t)b * KK + j0 + r) * 128;
        float4 a = x0[r], c = x1[r];
        a.x *= v; a.y *= v; a.z *= v; a.w *= v;
        c.x *= v; c.y *= v; c.z *= v; c.w *= v;
        dst[lane] = a;
        dst[lane + 64] = c;
    }
}

extern "C" void kernel_launch(void* const* d_in, const int* in_sizes, int n_in,
                              void* d_out, int out_size, void* d_ws, size_t ws_size,
                              hipStream_t stream) {
    const float* h  = (const float*)d_in[0];
    const float* sf = (const float*)d_in[1];
    float* out = (float*)d_out;
    u64* keys = (u64*)d_ws;    // 1 MiB of workspace

    score_kernel<<<4096, 256, 0, stream>>>(h, sf, keys);
    sortdir_kernel<<<64, 256, 0, stream>>>(keys);            // 16 alt-dir 2048-runs/batch
    global_ce_kernel<<<256, 256, 0, stream>>>(keys, 4096, 2048);
    finish_kernel<<<64, 256, 0, stream>>>(keys, 4096);       // -> 8 alt-dir 4096-runs
    global_ce_kernel<<<256, 256, 0, stream>>>(keys, 8192, 4096);
    global_ce_kernel<<<256, 256, 0, stream>>>(keys, 8192, 2048);
    finish_kernel<<<64, 256, 0, stream>>>(keys, 8192);       // -> 4 alt-dir 8192-runs
    topkAB_kernel<<<8, 1024, 0, stream>>>(keys);             // (asc,desc) pairs -> 2 asc runs
    topk_rev_kernel<<<4, 1024, 0, stream>>>(keys);           // 2 asc runs -> final top-8192
    gather_kernel<<<2048, 256, 0, stream>>>(h, keys, out);
}